// Round 15
// baseline (1003.131 us; speedup 1.0000x reference)
//
#include <hip/hip_runtime.h>

#define NB 8
#define TT 24
#define NN 4000
#define FF 32
#define HH 128
#define EE 64000

typedef float f32x4 __attribute__((ext_vector_type(4)));
typedef short bf16x8 __attribute__((ext_vector_type(8)));
#define MFMA16(a, b, c) __builtin_amdgcn_mfma_f32_16x16x32_bf16(a, b, c, 0, 0, 0)

__device__ __forceinline__ float fsig(float x) {
  return __builtin_amdgcn_rcpf(1.0f + __expf(-x));
}
__device__ __forceinline__ float ftanh(float x) {
  return 1.0f - 2.0f * __builtin_amdgcn_rcpf(__expf(2.0f * x) + 1.0f);
}

__device__ __forceinline__ unsigned short rne16(float x, float* hif) {
  unsigned u = __float_as_uint(x);
  unsigned r = (u + 0x7FFFu + ((u >> 16) & 1u)) >> 16;
  *hif = __uint_as_float(r << 16);
  return (unsigned short)r;
}

__device__ __forceinline__ unsigned rnd_top(float x) {
  unsigned u = __float_as_uint(x);
  return u + 0x7FFFu + ((u >> 16) & 1u);
}

// ---------- fused setup (weights pack + bias + ecnt/fillc zero) and x pre-split ----------
// blocks [0,418): setup work items; blocks [418, 12418): xsplit.
__global__ __launch_bounds__(256) void setup_xsplit_kernel(
    const float* __restrict__ x, const float* __restrict__ W_ih, const float* __restrict__ W_hh,
    const float* __restrict__ b_ih, const float* __restrict__ b_hh,
    const float* __restrict__ gcn_W,
    unsigned short* __restrict__ Wbh_hi, unsigned short* __restrict__ Wbh_lo,
    unsigned short* __restrict__ Wbi_hi, unsigned short* __restrict__ Wbi_lo,
    float* __restrict__ gcn_WT, float* __restrict__ bias,
    int* __restrict__ ecnt, int* __restrict__ fillc,
    unsigned short* __restrict__ xpk) {
  if (blockIdx.x < 418) {
    int idx = blockIdx.x * 256 + threadIdx.x;
    if (idx < 65536) {
      int e = idx & 7, l = (idx >> 3) & 63, ks = (idx >> 9) & 3, nt = idx >> 11;
      int gate = nt * 16 + (l & 15);
      int k = ks * 32 + (l >> 4) * 8 + e;
      float wv = W_hh[gate * 128 + k];
      float hif, d;
      unsigned short hb = rne16(wv, &hif);
      unsigned short lb = rne16(wv - hif, &d);
      Wbh_hi[idx] = hb;
      Wbh_lo[idx] = lb;
    } else if (idx < 65536 + 16384) {
      int p = idx - 65536;
      int e = p & 7, l = (p >> 3) & 63, nt = p >> 9;
      int gate = nt * 16 + (l & 15);
      int k = (l >> 4) * 8 + e;
      float wv = W_ih[gate * 32 + k];
      float hif, d;
      unsigned short hb = rne16(wv, &hif);
      unsigned short lb = rne16(wv - hif, &d);
      Wbi_hi[p] = hb;
      Wbi_lo[p] = lb;
    } else if (idx < 65536 + 16384 + 16384) {
      int p = idx - 65536 - 16384;
      int g = p & 127, k = p >> 7;
      gcn_WT[p] = gcn_W[g * 128 + k];
    } else if (idx < 65536 + 16384 + 16384 + 512) {
      int g = idx - (65536 + 16384 + 16384);
      bias[g] = b_ih[g] + b_hh[g];
    } else if (idx < 65536 + 16384 + 16384 + 512 + NN) {
      ecnt[idx - (65536 + 16384 + 16384 + 512)] = 0;
    } else if (idx < 65536 + 16384 + 16384 + 512 + 2 * NN) {
      fillc[idx - (65536 + 16384 + 16384 + 512 + NN)] = 0;
    }
  } else {
    int gid = (blockIdx.x - 418) * 256 + threadIdx.x;  // exactly 2000*24*64
    int l = gid & 63;
    int t = (gid >> 6) % TT;
    int rt = gid / (TT * 64);
    int col = l & 15, kc = l >> 4;
    int r = rt * 16 + col;  // NN%16==0 -> tile never straddles batch
    int b = (rt * 16) / NN;
    int n = r - b * NN;
    const float* src = x + (((size_t)b * TT + t) * NN + n) * FF + kc * 8;
    float4 p0 = *(const float4*)src;
    float4 p1 = *(const float4*)(src + 4);
    float xf[8] = {p0.x, p0.y, p0.z, p0.w, p1.x, p1.y, p1.z, p1.w};
    bf16x8 vh, vl;
#pragma unroll
    for (int e = 0; e < 8; ++e) {
      float hif, d;
      vh[e] = (short)rne16(xf[e], &hif);
      vl[e] = (short)rne16(xf[e] - hif, &d);
    }
    size_t ob = (size_t)(rt * TT + t) * 1024 + l * 8;
    *(bf16x8*)(xpk + ob) = vh;
    *(bf16x8*)(xpk + ob + 512) = vl;
  }
}

// ---------- LSTM via split-bf16 MFMA: 4 waves, 32 seqs/block, 1000 blocks ----------
// Output tiles processed in TWO sequential halves (u=0,1) so only acc[2][4]=32 regs are
// live at once; with __launch_bounds__(256,2) (2 blocks/CU class -> <=256 total regs/wave)
// this fits 2 waves/SIMD -> latency hiding (r14 ran 1 wave/SIMD, occupancy 11%).
// Half u: wave w owns tiles nt = 8g+4u+w (g=0..3) = gate g, j-block jb = w+4u.
// Bias enters as MFMA C-operand at ks==0. h frags re-read from LDS per half.
__global__ __launch_bounds__(256, 2) void lstm_kernel(
    const unsigned short* __restrict__ xpk,
    const unsigned short* __restrict__ Wbh_hi, const unsigned short* __restrict__ Wbh_lo,
    const unsigned short* __restrict__ Wbi_hi, const unsigned short* __restrict__ Wbi_lo,
    const float* __restrict__ bias,
    float* __restrict__ h_out) {
  __shared__ unsigned short hbuf[2][2][32 * 128];  // [buf][hi/lo][row*128+j] : 32 KB
  const int tid = threadIdx.x;
  const int w = tid >> 6, l = tid & 63;
  const int col = l & 15, kc = l >> 4;
  const int blk = blockIdx.x;

  {
    uint4* p0 = (uint4*)&hbuf[0][0][0];
    for (int i = tid; i < 1024; i += 256) p0[i] = make_uint4(0, 0, 0, 0);
  }

  float c[2][2][4];  // [sq][u][r]
#pragma unroll
  for (int sq = 0; sq < 2; ++sq)
#pragma unroll
    for (int u = 0; u < 2; ++u)
#pragma unroll
      for (int r = 0; r < 4; ++r) c[sq][u][r] = 0.0f;

  __syncthreads();

  for (int t = 0; t < TT; ++t) {
    const char* hr_hi = (const char*)&hbuf[t & 1][0][0];
    const char* hr_lo = (const char*)&hbuf[t & 1][1][0];
    char* hw_hi = (char*)&hbuf[(t + 1) & 1][0][0];
    char* hw_lo = (char*)&hbuf[(t + 1) & 1][1][0];

    // x fragments (pre-split) — loaded once, used by both halves
    bf16x8 xh[2], xl[2];
#pragma unroll
    for (int sq = 0; sq < 2; ++sq) {
      const unsigned short* xb = xpk + ((size_t)(blk * 2 + sq) * TT + t) * 1024 + l * 8;
      xh[sq] = *(const bf16x8*)xb;
      xl[sq] = *(const bf16x8*)(xb + 512);
    }

#pragma unroll
    for (int u = 0; u < 2; ++u) {
      f32x4 acc[2][4];  // [sq][g] — only one half live at a time

      __builtin_amdgcn_s_setprio(1);
      // recurrence: W_hh(A) x h(B), split-bf16 (3 MFMA per tile-pair)
#pragma unroll
      for (int ks = 0; ks < 4; ++ks) {
        bf16x8 bh[2], bl_[2];
#pragma unroll
        for (int sq = 0; sq < 2; ++sq) {
          int off = (16 * sq + col) * 256 + (((4 * ks + kc) ^ col) << 4);
          bh[sq] = *(const bf16x8*)(hr_hi + off);
          bl_[sq] = *(const bf16x8*)(hr_lo + off);
        }
#pragma unroll
        for (int g = 0; g < 4; ++g) {
          int nt = 8 * g + 4 * u + w;
          size_t wo = ((size_t)(nt * 4 + ks) * 64 + l) * 8;
          bf16x8 wh = *(const bf16x8*)(Wbh_hi + wo);
          bf16x8 wl = *(const bf16x8*)(Wbh_lo + wo);
          f32x4 cseed;
          if (ks == 0)
            cseed = *(const f32x4*)(bias + g * 128 + (4 * u + w) * 16 + 4 * kc);
#pragma unroll
          for (int sq = 0; sq < 2; ++sq) {
            acc[sq][g] = MFMA16(wh, bh[sq], ks == 0 ? cseed : acc[sq][g]);
            acc[sq][g] = MFMA16(wh, bl_[sq], acc[sq][g]);
            acc[sq][g] = MFMA16(wl, bh[sq], acc[sq][g]);
          }
        }
      }
      // input projection: W_ih(A) x x(B)
#pragma unroll
      for (int g = 0; g < 4; ++g) {
        int nt = 8 * g + 4 * u + w;
        size_t wo = ((size_t)nt * 64 + l) * 8;
        bf16x8 wh = *(const bf16x8*)(Wbi_hi + wo);
        bf16x8 wl = *(const bf16x8*)(Wbi_lo + wo);
#pragma unroll
        for (int sq = 0; sq < 2; ++sq) {
          acc[sq][g] = MFMA16(wh, xh[sq], acc[sq][g]);
          acc[sq][g] = MFMA16(wh, xl[sq], acc[sq][g]);
          acc[sq][g] = MFMA16(wl, xh[sq], acc[sq][g]);
        }
      }
      __builtin_amdgcn_s_setprio(0);

      // epilogue for this half: gates (i,f,g,o), state update, swizzled b64 LDS writes
      int jb = w + 4 * u;
#pragma unroll
      for (int sq = 0; sq < 2; ++sq) {
        unsigned uh[4], ul[4];
        float hv[4];
#pragma unroll
        for (int r = 0; r < 4; ++r) {
          float iv = fsig(acc[sq][0][r]);
          float fv = fsig(acc[sq][1][r]);
          float gv = ftanh(acc[sq][2][r]);
          float ov = fsig(acc[sq][3][r]);
          float cc = fv * c[sq][u][r] + iv * gv;
          c[sq][u][r] = cc;
          float hh = ov * ftanh(cc);
          hv[r] = hh;
          unsigned uu = __float_as_uint(hh);
          uh[r] = uu;  // hi = trunc bf16 (bytes 2,3)
          float hif = __uint_as_float(uu & 0xFFFF0000u);
          ul[r] = rnd_top(hh - hif);  // lo = RNE bf16 in top bits
        }
        uint2 phi, plo;
        phi.x = __builtin_amdgcn_perm(uh[1], uh[0], 0x07060302u);
        phi.y = __builtin_amdgcn_perm(uh[3], uh[2], 0x07060302u);
        plo.x = __builtin_amdgcn_perm(ul[1], ul[0], 0x07060302u);
        plo.y = __builtin_amdgcn_perm(ul[3], ul[2], 0x07060302u);
        int row = 16 * sq + col;
        int cs = (2 * jb + (kc >> 1)) ^ col;
        int woff = row * 256 + cs * 16 + 8 * (kc & 1);
        *(uint2*)(hw_hi + woff) = phi;
        *(uint2*)(hw_lo + woff) = plo;
        if (t == TT - 1) {
          int rowg = blk * 32 + 16 * sq + col;
          *(float4*)&h_out[(size_t)rowg * HH + 16 * jb + 4 * kc] =
              make_float4(hv[0], hv[1], hv[2], hv[3]);
        }
      }
    }
    __syncthreads();
  }
}

// ---------- GCN: CSR build + gather (no atomics in hot path) ----------
__global__ void hist_kernel(const int* __restrict__ ei, int* __restrict__ ecnt) {
  int e = blockIdx.x * 256 + threadIdx.x;
  if (e < EE) atomicAdd(&ecnt[ei[EE + e]], 1);
}

// single-block Hillis-Steele scan over 4096 (NN=4000 padded); also computes dinv = (ecnt+1)^-1/2
__global__ __launch_bounds__(1024) void scan_kernel(const int* __restrict__ ecnt,
                                                    int* __restrict__ rowptr,
                                                    float* __restrict__ dinv) {
  __shared__ int s[4096];
  int tid = threadIdx.x;
  for (int i = tid; i < 4096; i += 1024) {
    int v = (i < NN) ? ecnt[i] : 0;
    s[i] = v;
    if (i < NN) dinv[i] = 1.0f / sqrtf((float)v + 1.0f);  // deg = in-degree + self-loop
  }
  __syncthreads();
  for (int off = 1; off < 4096; off <<= 1) {
    int v[4];
#pragma unroll
    for (int k = 0; k < 4; ++k) {
      int i = tid + k * 1024;
      v[k] = s[i] + ((i >= off) ? s[i - off] : 0);
    }
    __syncthreads();
#pragma unroll
    for (int k = 0; k < 4; ++k) s[tid + k * 1024] = v[k];
    __syncthreads();
  }
  for (int i = tid; i <= NN; i += 1024) rowptr[i] = (i == 0) ? 0 : s[i - 1];
}

__global__ void fill_kernel(const int* __restrict__ ei, const float* __restrict__ dinv,
                            const int* __restrict__ rowptr, int* __restrict__ fillc,
                            int2* __restrict__ epk) {
  int e = blockIdx.x * 256 + threadIdx.x;
  if (e >= EE) return;
  int s = ei[e], d = ei[EE + e];
  int pos = rowptr[d] + atomicAdd(&fillc[d], 1);
  float nrm = dinv[s] * dinv[d];
  epk[pos] = make_int2(s, __float_as_int(nrm));
}

// xw[b,n,g] = sum_k h[b,n,k] * gcn_W[g,k]  ; 8 rows per block
__global__ __launch_bounds__(128) void xw_kernel(const float* __restrict__ h,
                                                 const float* __restrict__ gcn_WT,
                                                 float* __restrict__ xw) {
  const int r0 = blockIdx.x * 8;
  const int g = threadIdx.x;
  __shared__ float hs[8][HH];
  for (int m = 0; m < 8; ++m) hs[m][g] = h[(size_t)(r0 + m) * HH + g];
  __syncthreads();
  float acc[8] = {0, 0, 0, 0, 0, 0, 0, 0};
#pragma unroll 4
  for (int k = 0; k < HH; ++k) {
    float w = gcn_WT[k * HH + g];
#pragma unroll
    for (int m = 0; m < 8; ++m) acc[m] += hs[m][k] * w;
  }
  for (int m = 0; m < 8; ++m) xw[(size_t)(r0 + m) * HH + g] = acc[m];
}

// gather + self-loop + bias + relu + both heads, fused. 1 block = 1 dst node, 128 threads.
__global__ __launch_bounds__(128) void gather_final_kernel(
    const float* __restrict__ xw, const float* __restrict__ dinv,
    const int* __restrict__ rowptr, const int2* __restrict__ epk,
    const float* __restrict__ gcn_b,
    const float* __restrict__ fcw_c, const float* __restrict__ fcb_c,
    const float* __restrict__ fcw_i, const float* __restrict__ fcb_i,
    float* __restrict__ out) {
  const int d = blockIdx.x;
  const int j = threadIdx.x;
  float acc[NB];
#pragma unroll
  for (int b = 0; b < NB; ++b) acc[b] = 0.0f;
  const int p0 = rowptr[d], p1 = rowptr[d + 1];
  for (int p = p0; p < p1; ++p) {
    int2 ep = epk[p];
    int s = ep.x;
    float nrm = __int_as_float(ep.y);
#pragma unroll
    for (int b = 0; b < NB; ++b)
      acc[b] += xw[((size_t)b * NN + s) * HH + j] * nrm;
  }
  float sn = dinv[d] * dinv[d];
  float bj = gcn_b[j], wc = fcw_c[j], wi = fcw_i[j];
  __shared__ float red[2][NB][2];
  int lane = j & 63, wv = j >> 6;
#pragma unroll
  for (int b = 0; b < NB; ++b) {
    float v = acc[b] + xw[((size_t)b * NN + d) * HH + j] * sn + bj;
    v = fmaxf(v, 0.0f);
    float sc = v * wc, si = v * wi;
#pragma unroll
    for (int off = 32; off > 0; off >>= 1) {
      sc += __shfl_down(sc, off);
      si += __shfl_down(si, off);
    }
    if (lane == 0) {
      red[wv][b][0] = sc;
      red[wv][b][1] = si;
    }
  }
  __syncthreads();
  if (j < NB) {
    out[(size_t)j * NN + d] = red[0][j][0] + red[1][j][0] + fcb_c[0];
    out[(size_t)(NB + j) * NN + d] = red[0][j][1] + red[1][j][1] + fcb_i[0];
  }
}

extern "C" void kernel_launch(void* const* d_in, const int* in_sizes, int n_in,
                              void* d_out, int out_size, void* d_ws, size_t ws_size,
                              hipStream_t stream) {
  const float* x     = (const float*)d_in[0];
  const int*   ei    = (const int*)d_in[1];
  const float* W_ih  = (const float*)d_in[2];
  const float* W_hh  = (const float*)d_in[3];
  const float* b_ih  = (const float*)d_in[4];
  const float* b_hh  = (const float*)d_in[5];
  const float* gcn_W = (const float*)d_in[6];
  const float* gcn_b = (const float*)d_in[7];
  const float* fcw_c = (const float*)d_in[8];
  const float* fcb_c = (const float*)d_in[9];
  const float* fcw_i = (const float*)d_in[10];
  const float* fcb_i = (const float*)d_in[11];
  float* out = (float*)d_out;

  char* cur = (char*)d_ws;
  unsigned short* Wbh_hi = (unsigned short*)cur; cur += 65536 * 2;
  unsigned short* Wbh_lo = (unsigned short*)cur; cur += 65536 * 2;
  unsigned short* Wbi_hi = (unsigned short*)cur; cur += 16384 * 2;
  unsigned short* Wbi_lo = (unsigned short*)cur; cur += 16384 * 2;
  float* gcn_WT = (float*)cur; cur += 16384 * 4;
  float* bias   = (float*)cur; cur += 512 * 4;
  float* dinv   = (float*)cur; cur += 4096 * 4;
  int*   ecnt   = (int*)cur;   cur += 4096 * 4;
  int*   fillc  = (int*)cur;   cur += 4096 * 4;
  int*   rowptr = (int*)cur;   cur += 8192 * 4;
  int2*  epk    = (int2*)cur;  cur += (size_t)EE * 8;
  float* h_all  = (float*)cur; cur += (size_t)4096000 * 4;
  // overlay: xpk (98.3 MB, live only during lstm) | xw (live after lstm)
  unsigned short* xpk = (unsigned short*)cur;  // 2000*24*2*512 ushorts
  float* xw = (float*)cur;                     // 4,096,000 floats

  setup_xsplit_kernel<<<12418, 256, 0, stream>>>(x, W_ih, W_hh, b_ih, b_hh, gcn_W,
                                                 Wbh_hi, Wbh_lo, Wbi_hi, Wbi_lo,
                                                 gcn_WT, bias, ecnt, fillc, xpk);
  lstm_kernel<<<(NB * NN) / 32, 256, 0, stream>>>(xpk, Wbh_hi, Wbh_lo, Wbi_hi, Wbi_lo,
                                                  bias, h_all);
  hist_kernel<<<EE / 256, 256, 0, stream>>>(ei, ecnt);
  scan_kernel<<<1, 1024, 0, stream>>>(ecnt, rowptr, dinv);
  fill_kernel<<<EE / 256, 256, 0, stream>>>(ei, dinv, rowptr, fillc, epk);
  xw_kernel<<<(NB * NN) / 8, 128, 0, stream>>>(h_all, gcn_WT, xw);
  gather_final_kernel<<<NN, 128, 0, stream>>>(xw, dinv, rowptr, epk, gcn_b,
                                              fcw_c, fcb_c, fcw_i, fcb_i, out);
}

// Round 16
// 460.134 us; speedup vs baseline: 2.1801x; 2.1801x over previous
//
#include <hip/hip_runtime.h>

#define NB 8
#define TT 24
#define NN 4000
#define FF 32
#define HH 128
#define EE 64000

typedef float f32x4 __attribute__((ext_vector_type(4)));
typedef short bf16x8 __attribute__((ext_vector_type(8)));
#define MFMA16(a, b, c) __builtin_amdgcn_mfma_f32_16x16x32_bf16(a, b, c, 0, 0, 0)

__device__ __forceinline__ float fsig(float x) {
  return __builtin_amdgcn_rcpf(1.0f + __expf(-x));
}
__device__ __forceinline__ float ftanh(float x) {
  return 1.0f - 2.0f * __builtin_amdgcn_rcpf(__expf(2.0f * x) + 1.0f);
}

__device__ __forceinline__ unsigned short rne16(float x, float* hif) {
  unsigned u = __float_as_uint(x);
  unsigned r = (u + 0x7FFFu + ((u >> 16) & 1u)) >> 16;
  *hif = __uint_as_float(r << 16);
  return (unsigned short)r;
}

__device__ __forceinline__ unsigned rnd_top(float x) {
  unsigned u = __float_as_uint(x);
  return u + 0x7FFFu + ((u >> 16) & 1u);
}

// ---------- fused setup (weights pack + bias + ecnt/fillc zero) and x pre-split ----------
// blocks [0,418): setup work items; blocks [418, 12418): xsplit.
__global__ __launch_bounds__(256) void setup_xsplit_kernel(
    const float* __restrict__ x, const float* __restrict__ W_ih, const float* __restrict__ W_hh,
    const float* __restrict__ b_ih, const float* __restrict__ b_hh,
    const float* __restrict__ gcn_W,
    unsigned short* __restrict__ Wbh_hi, unsigned short* __restrict__ Wbh_lo,
    unsigned short* __restrict__ Wbi_hi, unsigned short* __restrict__ Wbi_lo,
    float* __restrict__ gcn_WT, float* __restrict__ bias,
    int* __restrict__ ecnt, int* __restrict__ fillc,
    unsigned short* __restrict__ xpk) {
  if (blockIdx.x < 418) {
    int idx = blockIdx.x * 256 + threadIdx.x;
    if (idx < 65536) {
      int e = idx & 7, l = (idx >> 3) & 63, ks = (idx >> 9) & 3, nt = idx >> 11;
      int gate = nt * 16 + (l & 15);
      int k = ks * 32 + (l >> 4) * 8 + e;
      float wv = W_hh[gate * 128 + k];
      float hif, d;
      unsigned short hb = rne16(wv, &hif);
      unsigned short lb = rne16(wv - hif, &d);
      Wbh_hi[idx] = hb;
      Wbh_lo[idx] = lb;
    } else if (idx < 65536 + 16384) {
      int p = idx - 65536;
      int e = p & 7, l = (p >> 3) & 63, nt = p >> 9;
      int gate = nt * 16 + (l & 15);
      int k = (l >> 4) * 8 + e;
      float wv = W_ih[gate * 32 + k];
      float hif, d;
      unsigned short hb = rne16(wv, &hif);
      unsigned short lb = rne16(wv - hif, &d);
      Wbi_hi[p] = hb;
      Wbi_lo[p] = lb;
    } else if (idx < 65536 + 16384 + 16384) {
      int p = idx - 65536 - 16384;
      int g = p & 127, k = p >> 7;
      gcn_WT[p] = gcn_W[g * 128 + k];
    } else if (idx < 65536 + 16384 + 16384 + 512) {
      int g = idx - (65536 + 16384 + 16384);
      bias[g] = b_ih[g] + b_hh[g];
    } else if (idx < 65536 + 16384 + 16384 + 512 + NN) {
      ecnt[idx - (65536 + 16384 + 16384 + 512)] = 0;
    } else if (idx < 65536 + 16384 + 16384 + 512 + 2 * NN) {
      fillc[idx - (65536 + 16384 + 16384 + 512 + NN)] = 0;
    }
  } else {
    int gid = (blockIdx.x - 418) * 256 + threadIdx.x;  // exactly 2000*24*64
    int l = gid & 63;
    int t = (gid >> 6) % TT;
    int rt = gid / (TT * 64);
    int col = l & 15, kc = l >> 4;
    int r = rt * 16 + col;  // NN%16==0 -> tile never straddles batch
    int b = (rt * 16) / NN;
    int n = r - b * NN;
    const float* src = x + (((size_t)b * TT + t) * NN + n) * FF + kc * 8;
    float4 p0 = *(const float4*)src;
    float4 p1 = *(const float4*)(src + 4);
    float xf[8] = {p0.x, p0.y, p0.z, p0.w, p1.x, p1.y, p1.z, p1.w};
    bf16x8 vh, vl;
#pragma unroll
    for (int e = 0; e < 8; ++e) {
      float hif, d;
      vh[e] = (short)rne16(xf[e], &hif);
      vl[e] = (short)rne16(xf[e] - hif, &d);
    }
    size_t ob = (size_t)(rt * TT + t) * 1024 + l * 8;
    *(bf16x8*)(xpk + ob) = vh;
    *(bf16x8*)(xpk + ob + 512) = vl;
  }
}

// ---------- LSTM via split-bf16 MFMA: 4 waves, 32 seqs/block, 1000 blocks ----------
// Two sequential output halves (u=0,1): only acc[2][4]=32 accumulator regs live at once,
// total live ~<=190 arch regs -> fits the default 256-class with NO AGPR allocation
// -> 256 total/wave -> 2 waves/SIMD (2 blocks/CU) for latency hiding.
// NO launch_bounds min-clause: any clause value N forces the 256/N arch class (verified
// r5/r9/r15) and spills. Half u: wave w owns tiles nt = 8g+4u+w = gate g, j-block jb=w+4u.
// Bias enters as MFMA C-operand at ks==0. h frags re-read from LDS per half.
__global__ __launch_bounds__(256) void lstm_kernel(
    const unsigned short* __restrict__ xpk,
    const unsigned short* __restrict__ Wbh_hi, const unsigned short* __restrict__ Wbh_lo,
    const unsigned short* __restrict__ Wbi_hi, const unsigned short* __restrict__ Wbi_lo,
    const float* __restrict__ bias,
    float* __restrict__ h_out) {
  __shared__ unsigned short hbuf[2][2][32 * 128];  // [buf][hi/lo][row*128+j] : 32 KB
  const int tid = threadIdx.x;
  const int w = tid >> 6, l = tid & 63;
  const int col = l & 15, kc = l >> 4;
  const int blk = blockIdx.x;

  {
    uint4* p0 = (uint4*)&hbuf[0][0][0];
    for (int i = tid; i < 1024; i += 256) p0[i] = make_uint4(0, 0, 0, 0);
  }

  float c[2][2][4];  // [sq][u][r]
#pragma unroll
  for (int sq = 0; sq < 2; ++sq)
#pragma unroll
    for (int u = 0; u < 2; ++u)
#pragma unroll
      for (int r = 0; r < 4; ++r) c[sq][u][r] = 0.0f;

  __syncthreads();

  for (int t = 0; t < TT; ++t) {
    const char* hr_hi = (const char*)&hbuf[t & 1][0][0];
    const char* hr_lo = (const char*)&hbuf[t & 1][1][0];
    char* hw_hi = (char*)&hbuf[(t + 1) & 1][0][0];
    char* hw_lo = (char*)&hbuf[(t + 1) & 1][1][0];

    // x fragments (pre-split) — loaded once, used by both halves
    bf16x8 xh[2], xl[2];
#pragma unroll
    for (int sq = 0; sq < 2; ++sq) {
      const unsigned short* xb = xpk + ((size_t)(blk * 2 + sq) * TT + t) * 1024 + l * 8;
      xh[sq] = *(const bf16x8*)xb;
      xl[sq] = *(const bf16x8*)(xb + 512);
    }

#pragma unroll
    for (int u = 0; u < 2; ++u) {
      f32x4 acc[2][4];  // [sq][g] — only one half live at a time

      __builtin_amdgcn_s_setprio(1);
      // recurrence: W_hh(A) x h(B), split-bf16 (3 MFMA per tile-pair)
#pragma unroll
      for (int ks = 0; ks < 4; ++ks) {
        bf16x8 bh[2], bl_[2];
#pragma unroll
        for (int sq = 0; sq < 2; ++sq) {
          int off = (16 * sq + col) * 256 + (((4 * ks + kc) ^ col) << 4);
          bh[sq] = *(const bf16x8*)(hr_hi + off);
          bl_[sq] = *(const bf16x8*)(hr_lo + off);
        }
#pragma unroll
        for (int g = 0; g < 4; ++g) {
          int nt = 8 * g + 4 * u + w;
          size_t wo = ((size_t)(nt * 4 + ks) * 64 + l) * 8;
          bf16x8 wh = *(const bf16x8*)(Wbh_hi + wo);
          bf16x8 wl = *(const bf16x8*)(Wbh_lo + wo);
          f32x4 cseed;
          if (ks == 0)
            cseed = *(const f32x4*)(bias + g * 128 + (4 * u + w) * 16 + 4 * kc);
#pragma unroll
          for (int sq = 0; sq < 2; ++sq) {
            acc[sq][g] = MFMA16(wh, bh[sq], ks == 0 ? cseed : acc[sq][g]);
            acc[sq][g] = MFMA16(wh, bl_[sq], acc[sq][g]);
            acc[sq][g] = MFMA16(wl, bh[sq], acc[sq][g]);
          }
        }
      }
      // input projection: W_ih(A) x x(B)
#pragma unroll
      for (int g = 0; g < 4; ++g) {
        int nt = 8 * g + 4 * u + w;
        size_t wo = ((size_t)nt * 64 + l) * 8;
        bf16x8 wh = *(const bf16x8*)(Wbi_hi + wo);
        bf16x8 wl = *(const bf16x8*)(Wbi_lo + wo);
#pragma unroll
        for (int sq = 0; sq < 2; ++sq) {
          acc[sq][g] = MFMA16(wh, xh[sq], acc[sq][g]);
          acc[sq][g] = MFMA16(wh, xl[sq], acc[sq][g]);
          acc[sq][g] = MFMA16(wl, xh[sq], acc[sq][g]);
        }
      }
      __builtin_amdgcn_s_setprio(0);

      // epilogue for this half: gates (i,f,g,o), state update, swizzled b64 LDS writes
      int jb = w + 4 * u;
#pragma unroll
      for (int sq = 0; sq < 2; ++sq) {
        unsigned uh[4], ul[4];
        float hv[4];
#pragma unroll
        for (int r = 0; r < 4; ++r) {
          float iv = fsig(acc[sq][0][r]);
          float fv = fsig(acc[sq][1][r]);
          float gv = ftanh(acc[sq][2][r]);
          float ov = fsig(acc[sq][3][r]);
          float cc = fv * c[sq][u][r] + iv * gv;
          c[sq][u][r] = cc;
          float hh = ov * ftanh(cc);
          hv[r] = hh;
          unsigned uu = __float_as_uint(hh);
          uh[r] = uu;  // hi = trunc bf16 (bytes 2,3)
          float hif = __uint_as_float(uu & 0xFFFF0000u);
          ul[r] = rnd_top(hh - hif);  // lo = RNE bf16 in top bits
        }
        uint2 phi, plo;
        phi.x = __builtin_amdgcn_perm(uh[1], uh[0], 0x07060302u);
        phi.y = __builtin_amdgcn_perm(uh[3], uh[2], 0x07060302u);
        plo.x = __builtin_amdgcn_perm(ul[1], ul[0], 0x07060302u);
        plo.y = __builtin_amdgcn_perm(ul[3], ul[2], 0x07060302u);
        int row = 16 * sq + col;
        int cs = (2 * jb + (kc >> 1)) ^ col;
        int woff = row * 256 + cs * 16 + 8 * (kc & 1);
        *(uint2*)(hw_hi + woff) = phi;
        *(uint2*)(hw_lo + woff) = plo;
        if (t == TT - 1) {
          int rowg = blk * 32 + 16 * sq + col;
          *(float4*)&h_out[(size_t)rowg * HH + 16 * jb + 4 * kc] =
              make_float4(hv[0], hv[1], hv[2], hv[3]);
        }
      }
    }
    __syncthreads();
  }
}

// ---------- GCN: CSR build + gather (no atomics in hot path) ----------
__global__ void hist_kernel(const int* __restrict__ ei, int* __restrict__ ecnt) {
  int e = blockIdx.x * 256 + threadIdx.x;
  if (e < EE) atomicAdd(&ecnt[ei[EE + e]], 1);
}

// single-block Hillis-Steele scan over 4096 (NN=4000 padded); also computes dinv = (ecnt+1)^-1/2
__global__ __launch_bounds__(1024) void scan_kernel(const int* __restrict__ ecnt,
                                                    int* __restrict__ rowptr,
                                                    float* __restrict__ dinv) {
  __shared__ int s[4096];
  int tid = threadIdx.x;
  for (int i = tid; i < 4096; i += 1024) {
    int v = (i < NN) ? ecnt[i] : 0;
    s[i] = v;
    if (i < NN) dinv[i] = 1.0f / sqrtf((float)v + 1.0f);  // deg = in-degree + self-loop
  }
  __syncthreads();
  for (int off = 1; off < 4096; off <<= 1) {
    int v[4];
#pragma unroll
    for (int k = 0; k < 4; ++k) {
      int i = tid + k * 1024;
      v[k] = s[i] + ((i >= off) ? s[i - off] : 0);
    }
    __syncthreads();
#pragma unroll
    for (int k = 0; k < 4; ++k) s[tid + k * 1024] = v[k];
    __syncthreads();
  }
  for (int i = tid; i <= NN; i += 1024) rowptr[i] = (i == 0) ? 0 : s[i - 1];
}

__global__ void fill_kernel(const int* __restrict__ ei, const float* __restrict__ dinv,
                            const int* __restrict__ rowptr, int* __restrict__ fillc,
                            int2* __restrict__ epk) {
  int e = blockIdx.x * 256 + threadIdx.x;
  if (e >= EE) return;
  int s = ei[e], d = ei[EE + e];
  int pos = rowptr[d] + atomicAdd(&fillc[d], 1);
  float nrm = dinv[s] * dinv[d];
  epk[pos] = make_int2(s, __float_as_int(nrm));
}

// xw[b,n,g] = sum_k h[b,n,k] * gcn_W[g,k]  ; 8 rows per block
__global__ __launch_bounds__(128) void xw_kernel(const float* __restrict__ h,
                                                 const float* __restrict__ gcn_WT,
                                                 float* __restrict__ xw) {
  const int r0 = blockIdx.x * 8;
  const int g = threadIdx.x;
  __shared__ float hs[8][HH];
  for (int m = 0; m < 8; ++m) hs[m][g] = h[(size_t)(r0 + m) * HH + g];
  __syncthreads();
  float acc[8] = {0, 0, 0, 0, 0, 0, 0, 0};
#pragma unroll 4
  for (int k = 0; k < HH; ++k) {
    float w = gcn_WT[k * HH + g];
#pragma unroll
    for (int m = 0; m < 8; ++m) acc[m] += hs[m][k] * w;
  }
  for (int m = 0; m < 8; ++m) xw[(size_t)(r0 + m) * HH + g] = acc[m];
}

// gather + self-loop + bias + relu + both heads, fused. 1 block = 1 dst node, 128 threads.
__global__ __launch_bounds__(128) void gather_final_kernel(
    const float* __restrict__ xw, const float* __restrict__ dinv,
    const int* __restrict__ rowptr, const int2* __restrict__ epk,
    const float* __restrict__ gcn_b,
    const float* __restrict__ fcw_c, const float* __restrict__ fcb_c,
    const float* __restrict__ fcw_i, const float* __restrict__ fcb_i,
    float* __restrict__ out) {
  const int d = blockIdx.x;
  const int j = threadIdx.x;
  float acc[NB];
#pragma unroll
  for (int b = 0; b < NB; ++b) acc[b] = 0.0f;
  const int p0 = rowptr[d], p1 = rowptr[d + 1];
  for (int p = p0; p < p1; ++p) {
    int2 ep = epk[p];
    int s = ep.x;
    float nrm = __int_as_float(ep.y);
#pragma unroll
    for (int b = 0; b < NB; ++b)
      acc[b] += xw[((size_t)b * NN + s) * HH + j] * nrm;
  }
  float sn = dinv[d] * dinv[d];
  float bj = gcn_b[j], wc = fcw_c[j], wi = fcw_i[j];
  __shared__ float red[2][NB][2];
  int lane = j & 63, wv = j >> 6;
#pragma unroll
  for (int b = 0; b < NB; ++b) {
    float v = acc[b] + xw[((size_t)b * NN + d) * HH + j] * sn + bj;
    v = fmaxf(v, 0.0f);
    float sc = v * wc, si = v * wi;
#pragma unroll
    for (int off = 32; off > 0; off >>= 1) {
      sc += __shfl_down(sc, off);
      si += __shfl_down(si, off);
    }
    if (lane == 0) {
      red[wv][b][0] = sc;
      red[wv][b][1] = si;
    }
  }
  __syncthreads();
  if (j < NB) {
    out[(size_t)j * NN + d] = red[0][j][0] + red[1][j][0] + fcb_c[0];
    out[(size_t)(NB + j) * NN + d] = red[0][j][1] + red[1][j][1] + fcb_i[0];
  }
}

extern "C" void kernel_launch(void* const* d_in, const int* in_sizes, int n_in,
                              void* d_out, int out_size, void* d_ws, size_t ws_size,
                              hipStream_t stream) {
  const float* x     = (const float*)d_in[0];
  const int*   ei    = (const int*)d_in[1];
  const float* W_ih  = (const float*)d_in[2];
  const float* W_hh  = (const float*)d_in[3];
  const float* b_ih  = (const float*)d_in[4];
  const float* b_hh  = (const float*)d_in[5];
  const float* gcn_W = (const float*)d_in[6];
  const float* gcn_b = (const float*)d_in[7];
  const float* fcw_c = (const float*)d_in[8];
  const float* fcb_c = (const float*)d_in[9];
  const float* fcw_i = (const float*)d_in[10];
  const float* fcb_i = (const float*)d_in[11];
  float* out = (float*)d_out;

  char* cur = (char*)d_ws;
  unsigned short* Wbh_hi = (unsigned short*)cur; cur += 65536 * 2;
  unsigned short* Wbh_lo = (unsigned short*)cur; cur += 65536 * 2;
  unsigned short* Wbi_hi = (unsigned short*)cur; cur += 16384 * 2;
  unsigned short* Wbi_lo = (unsigned short*)cur; cur += 16384 * 2;
  float* gcn_WT = (float*)cur; cur += 16384 * 4;
  float* bias   = (float*)cur; cur += 512 * 4;
  float* dinv   = (float*)cur; cur += 4096 * 4;
  int*   ecnt   = (int*)cur;   cur += 4096 * 4;
  int*   fillc  = (int*)cur;   cur += 4096 * 4;
  int*   rowptr = (int*)cur;   cur += 8192 * 4;
  int2*  epk    = (int2*)cur;  cur += (size_t)EE * 8;
  float* h_all  = (float*)cur; cur += (size_t)4096000 * 4;
  // overlay: xpk (98.3 MB, live only during lstm) | xw (live after lstm)
  unsigned short* xpk = (unsigned short*)cur;  // 2000*24*2*512 ushorts
  float* xw = (float*)cur;                     // 4,096,000 floats

  setup_xsplit_kernel<<<12418, 256, 0, stream>>>(x, W_ih, W_hh, b_ih, b_hh, gcn_W,
                                                 Wbh_hi, Wbh_lo, Wbi_hi, Wbi_lo,
                                                 gcn_WT, bias, ecnt, fillc, xpk);
  lstm_kernel<<<(NB * NN) / 32, 256, 0, stream>>>(xpk, Wbh_hi, Wbh_lo, Wbi_hi, Wbi_lo,
                                                  bias, h_all);
  hist_kernel<<<EE / 256, 256, 0, stream>>>(ei, ecnt);
  scan_kernel<<<1, 1024, 0, stream>>>(ecnt, rowptr, dinv);
  fill_kernel<<<EE / 256, 256, 0, stream>>>(ei, dinv, rowptr, fillc, epk);
  xw_kernel<<<(NB * NN) / 8, 128, 0, stream>>>(h_all, gcn_WT, xw);
  gather_final_kernel<<<NN, 128, 0, stream>>>(xw, dinv, rowptr, epk, gcn_b,
                                              fcw_c, fcb_c, fcw_i, fcb_i, out);
}